// Round 17
// baseline (94.193 us; speedup 1.0000x reference)
//
#include <hip/hip_runtime.h>
#include <hip/hip_fp16.h>
#include <math.h>

// GSSIM loss, persistent half-strip kernel (R17 = R14 + merged Sobel/H-sum).
// sg[] staging array eliminated (write-once-read-once): each of 304 balanced
// single-row units computes its 10 Sobel grads in registers from spt and does
// the horizontal sliding 7-sums directly -> hsAll. 2 barriers/tile (was 3),
// LDS 26496 B -> 6 blocks/CU (was 5). Sobel recomputed 2.0x (pure VALU).
// Grid 2048 half-strips (256x32, 8 tiles).
// Per tile: [B] stage -> P3 fused Sobel+H-sums -> bar ->
//           P4 V-sums+SSIM -> [A] spt write -> bar.
// Kernel 2: deterministic f64 reduce -> 1 - mean.

constexpr int NT = 256;
constexpr float EPS_F = 1e-6f;
constexpr float C1S = 2401.0f * 0.0001f;  // C1 * 49^2
constexpr float C2S = 2401.0f * 0.0009f;  // C2 * 49^2

union U4 { uint4 u; __half2 h[4]; };
union F4U { float4 v; float a[4]; };

__device__ __forceinline__ __half2 h2swap(__half2 x) {
    unsigned u = __builtin_bit_cast(unsigned, x);
    u = (u >> 16) | (u << 16);
    return __builtin_bit_cast(__half2, u);
}

__device__ __forceinline__ float ssim_px(__half2 apt, __half2 ag, __half2 agg, __half2 agx) {
    float2 vpt = __half22float2(apt);
    float2 vg  = __half22float2(ag);
    float2 vgg = __half22float2(agg);
    float  vgx = __low2float(agx);
    float lum_n = 2.0f * vpt.x * vpt.y + C1S;
    float lum_d = vpt.x * vpt.x + vpt.y * vpt.y + C1S;
    float cs_n  = 2.0f * (49.0f * vgx - vg.x * vg.y) + C2S;
    float cs_d  = 49.0f * (vgg.x + vgg.y) - vg.x * vg.x - vg.y * vg.y + C2S;
    return lum_n * cs_n * __builtin_amdgcn_rcpf(lum_d * cs_d);
}

__global__ __launch_bounds__(NT, 4)
void gssim_strip(const float* __restrict__ pred, const float* __restrict__ target,
                 const float* __restrict__ mn_arr, const float* __restrict__ mx_arr,
                 float* __restrict__ partial) {
    constexpr int H = 512, W = 512;
    __shared__ alignas(16) __half2 spt[40][44];      // 7040 B, stride 44 == 12 mod 32
    __shared__ alignas(16) __half2 hsAll[38][32][4]; // 19456 B, rotated col=(c+k)&31
                                                     // total 26496 B -> 6 blocks/CU

    const int blk  = blockIdx.x;          // 0..2047
    const int b    = blk >> 5;            // image 0..63
    const int rem  = blk & 31;
    const int gy0  = (rem >> 1) * 32;     // strip top row
    const int tx0  = (rem & 1) * 8;       // first tile of this half-strip
    const int tid  = threadIdx.x;

    const float mn     = mn_arr[b];
    const float inv_dr = 1.0f / fmaxf(mx_arr[b] - mn, EPS_F);
    const __half2 mn2  = __float2half2_rn(mn);
    const __half2 inv2 = __float2half2_rn(inv_dr);
    const float* pimg = pred   + (size_t)b * H * W;
    const float* timg = target + (size_t)b * H * W;

    const bool rows_ok_all = (gy0 >= 4) && (gy0 + 35 < H);

    // staging: tid<200 owns input row pair (2*yr, 2*yr+1), col grp gS
    const int gS  = tid % 10;
    const int yr  = tid / 10;
    const int yS0 = 2 * yr, yS1 = yS0 + 1;
    const int gyS0 = gy0 - 4 + yS0;
    const int gyS1 = gyS0 + 1;
    const bool rok0 = (gyS0 >= 0 && gyS0 < H);
    const bool rok1 = (gyS1 >= 0 && gyS1 < H);
    const bool hasS = (tid < 200);

    F4U Pa0, Ta0, Pa1, Ta1;   // staged raw pixels (next tile)

    auto stage1m = [&](int gx0n, bool rowok, int gyI, F4U& P, F4U& T) {
        int gx = gx0n - 4 + 4 * gS;
        P.v = make_float4(0.f, 0.f, 0.f, 0.f);
        T.v = make_float4(0.f, 0.f, 0.f, 0.f);
        if (rowok) {
            if (gx >= 0 && gx + 4 <= W) {
                P.v = *reinterpret_cast<const float4*>(pimg + (size_t)gyI * W + gx);
                T.v = *reinterpret_cast<const float4*>(timg + (size_t)gyI * W + gx);
            } else {
#pragma unroll
                for (int c = 0; c < 4; ++c) {
                    int x = gx + c;
                    if (x >= 0 && x < W) {
                        P.a[c] = pimg[(size_t)gyI * W + x];
                        T.a[c] = timg[(size_t)gyI * W + x];
                    }
                }
            }
        }
    };
    auto stagePair = [&](int gx0n) {
        if (rows_ok_all && gx0n >= 4 && gx0n <= 448) {   // uniform fast path
            int gx = gx0n - 4 + 4 * gS;
            Pa0.v = *reinterpret_cast<const float4*>(pimg + (size_t)gyS0 * W + gx);
            Ta0.v = *reinterpret_cast<const float4*>(timg + (size_t)gyS0 * W + gx);
            Pa1.v = *reinterpret_cast<const float4*>(pimg + (size_t)gyS1 * W + gx);
            Ta1.v = *reinterpret_cast<const float4*>(timg + (size_t)gyS1 * W + gx);
        } else {
            stage1m(gx0n, rok0, gyS0, Pa0, Ta0);
            stage1m(gx0n, rok1, gyS1, Pa1, Ta1);
        }
    };

    auto normh2 = [&](float p, float t) {
        return __hmul2(__hsub2(__floats2half2_rn(p, t), mn2), inv2);
    };
    auto writePair = [&](int gx0n) {
        U4 w0, w1;
        if (rows_ok_all && gx0n >= 4 && gx0n <= 448) {   // uniform fast path
#pragma unroll
            for (int c = 0; c < 4; ++c) {
                w0.h[c] = normh2(Pa0.a[c], Ta0.a[c]);
                w1.h[c] = normh2(Pa1.a[c], Ta1.a[c]);
            }
        } else {
            int gx = gx0n - 4 + 4 * gS;
            const __half2 zero2l = __float2half2_rn(0.0f);
#pragma unroll
            for (int c = 0; c < 4; ++c) {
                int x = gx + c;
                bool okc = (x >= 0) && (x < W);
                w0.h[c] = (rok0 && okc) ? normh2(Pa0.a[c], Ta0.a[c]) : zero2l;
                w1.h[c] = (rok1 && okc) ? normh2(Pa1.a[c], Ta1.a[c]) : zero2l;
            }
        }
        *reinterpret_cast<uint4*>(&spt[yS0][4 * gS]) = w0.u;
        *reinterpret_cast<uint4*>(&spt[yS1][4 * gS]) = w1.u;
    };

    const __half2 two2  = __float2half2_rn(2.0f);
    const __half2 eps2  = __float2half2_rn(1e-6f);
    const __half2 zero2 = __float2half2_rn(0.0f);

    // prologue: stage + write first tile
    if (hasS) { stagePair(tx0 * 32); writePair(tx0 * 32); }
    __syncthreads();

    float accl = 0.0f;

    for (int tt = 0; tt < 8; ++tt) {
        const int gx0 = (tx0 + tt) * 32;
        const bool interior = rows_ok_all && (gx0 >= 32) && (gx0 <= 448);

        // ---- [B] issue next tile's loads (consumed after P4) ----
        if (tt < 7 && hasS) stagePair(gx0 + 32);

        // ---- P3: fused Sobel + horizontal sliding 7-sums; 304 units ----
        auto p3unit = [&](int t) {
            const int cg = t / 38;            // 0..7
            const int k  = t - cg * 38;       // grad row 0..37 (lane-consecutive)
            const int c0 = 4 * cg;            // output col base

            __half2 A[3][12];                 // spt rows k..k+2, cols c0..c0+11
#pragma unroll
            for (int r = 0; r < 3; ++r) {
#pragma unroll
                for (int q = 0; q < 3; ++q) {
                    U4 v; v.u = *reinterpret_cast<const uint4*>(&spt[k + r][c0 + 4 * q]);
                    A[r][4 * q] = v.h[0]; A[r][4 * q + 1] = v.h[1];
                    A[r][4 * q + 2] = v.h[2]; A[r][4 * q + 3] = v.h[3];
                }
            }

            __half2 grad[10];                 // grad cols c0..c0+9
            if (interior) {
#pragma unroll
                for (int jj = 0; jj < 10; ++jj) {
                    __half2 gxh = __hsub2(A[0][jj + 2], A[0][jj]);
                    gxh = __hfma2(two2, __hsub2(A[1][jj + 2], A[1][jj]), gxh);
                    gxh = __hadd2(gxh, __hsub2(A[2][jj + 2], A[2][jj]));
                    __half2 gyh = __hsub2(A[2][jj], A[0][jj]);
                    gyh = __hfma2(two2, __hsub2(A[2][jj + 1], A[0][jj + 1]), gyh);
                    gyh = __hadd2(gyh, __hsub2(A[2][jj + 2], A[0][jj + 2]));
                    grad[jj] = h2sqrt(__hfma2(gxh, gxh, __hfma2(gyh, gyh, eps2)));
                }
            } else {
                const int gr = gy0 + k - 3;
                const bool rowv = (gr >= 0 && gr < H);
#pragma unroll
                for (int jj = 0; jj < 10; ++jj) {
                    __half2 gxh = __hsub2(A[0][jj + 2], A[0][jj]);
                    gxh = __hfma2(two2, __hsub2(A[1][jj + 2], A[1][jj]), gxh);
                    gxh = __hadd2(gxh, __hsub2(A[2][jj + 2], A[2][jj]));
                    __half2 gyh = __hsub2(A[2][jj], A[0][jj]);
                    gyh = __hfma2(two2, __hsub2(A[2][jj + 1], A[0][jj + 1]), gyh);
                    gyh = __hadd2(gyh, __hsub2(A[2][jj + 2], A[0][jj + 2]));
                    __half2 g = h2sqrt(__hfma2(gxh, gxh, __hfma2(gyh, gyh, eps2)));
                    int gc = gx0 + c0 + jj - 3;
                    grad[jj] = (rowv && gc >= 0 && gc < W) ? g : zero2;
                }
            }

            // horizontal sliding 7-sums; gg/gx2 on the fly
            __half2 Hpt = A[1][1], Hg = grad[0];
            __half2 Hgg = __hmul2(grad[0], grad[0]);
            __half2 Hgx = __hmul2(grad[0], h2swap(grad[0]));
#pragma unroll
            for (int q = 1; q < 7; ++q) {
                Hpt = __hadd2(Hpt, A[1][q + 1]);
                Hg  = __hadd2(Hg,  grad[q]);
                Hgg = __hfma2(grad[q], grad[q], Hgg);
                Hgx = __hfma2(grad[q], h2swap(grad[q]), Hgx);
            }
            U4 w0;
            w0.h[0] = Hpt; w0.h[1] = Hg; w0.h[2] = Hgg; w0.h[3] = Hgx;
            *reinterpret_cast<uint4*>(&hsAll[k][(c0 + k) & 31][0]) = w0.u;
#pragma unroll
            for (int m = 1; m < 4; ++m) {
                __half2 gin = grad[m + 6], gout = grad[m - 1];
                Hpt = __hadd2(__hsub2(Hpt, A[1][m]), A[1][m + 7]);
                Hg  = __hadd2(__hsub2(Hg, gout), gin);
                Hgg = __hfma2(gin, gin, __hsub2(Hgg, __hmul2(gout, gout)));
                Hgx = __hfma2(gin, h2swap(gin), __hsub2(Hgx, __hmul2(gout, h2swap(gout))));
                U4 w;
                w.h[0] = Hpt; w.h[1] = Hg; w.h[2] = Hgg; w.h[3] = Hgx;
                *reinterpret_cast<uint4*>(&hsAll[k][(c0 + m + k) & 31][0]) = w.u;
            }
        };
        p3unit(tid);
        if (tid < 48) p3unit(tid + 256);
        __syncthreads();

        // ---- P4: per-column vertical sliding 7-sums + SSIM ----
        {
            const int ox = tid & 31;
            const int q  = tid >> 5;
            const int r0 = 4 * q;
            U4 win[10];
#pragma unroll
            for (int j = 0; j < 7; ++j) {
                int r = r0 + j;
                win[j].u = *reinterpret_cast<const uint4*>(&hsAll[r][(ox + r) & 31][0]);
            }
            __half2 Spt = win[0].h[0], Sg = win[0].h[1], Sgg = win[0].h[2], Sgx = win[0].h[3];
#pragma unroll
            for (int j = 1; j < 7; ++j) {
                Spt = __hadd2(Spt, win[j].h[0]);
                Sg  = __hadd2(Sg,  win[j].h[1]);
                Sgg = __hadd2(Sgg, win[j].h[2]);
                Sgx = __hadd2(Sgx, win[j].h[3]);
            }
            accl += ssim_px(Spt, Sg, Sgg, Sgx);
#pragma unroll
            for (int s = 1; s < 4; ++s) {
                int r = r0 + 6 + s;
                win[6 + s].u = *reinterpret_cast<const uint4*>(&hsAll[r][(ox + r) & 31][0]);
                Spt = __hadd2(__hsub2(Spt, win[s - 1].h[0]), win[6 + s].h[0]);
                Sg  = __hadd2(__hsub2(Sg,  win[s - 1].h[1]), win[6 + s].h[1]);
                Sgg = __hadd2(__hsub2(Sgg, win[s - 1].h[2]), win[6 + s].h[2]);
                Sgx = __hadd2(__hsub2(Sgx, win[s - 1].h[3]), win[6 + s].h[3]);
                accl += ssim_px(Spt, Sg, Sgg, Sgx);
            }
        }

        // ---- [A] write next tile's spt (all P3 reads done at the barrier) ----
        if (tt < 7 && hasS) writePair(gx0 + 32);
        __syncthreads();
    }

    // ---- block reduction (deterministic); scratch overlaid on spt ----
    float* red = reinterpret_cast<float*>(&spt[0][0]);
#pragma unroll
    for (int off = 32; off > 0; off >>= 1) accl += __shfl_down(accl, off, 64);
    if ((tid & 63) == 0) red[tid >> 6] = accl;
    __syncthreads();
    if (tid == 0) partial[blk] = red[0] + red[1] + red[2] + red[3];
}

__global__ __launch_bounds__(256)
void gssim_final(const float* __restrict__ partial, int n,
                 float* __restrict__ out, double inv_count) {
    __shared__ double sred[256];
    double acc = 0.0;
    for (int i = threadIdx.x; i < n; i += 256) acc += (double)partial[i];
    sred[threadIdx.x] = acc;
    __syncthreads();
    for (int s = 128; s > 0; s >>= 1) {
        if ((int)threadIdx.x < s) sred[threadIdx.x] += sred[threadIdx.x + s];
        __syncthreads();
    }
    if (threadIdx.x == 0) out[0] = (float)(1.0 - sred[0] * inv_count);
}

extern "C" void kernel_launch(void* const* d_in, const int* in_sizes, int n_in,
                              void* d_out, int out_size, void* d_ws, size_t ws_size,
                              hipStream_t stream) {
    const float* pred   = (const float*)d_in[0];
    const float* target = (const float*)d_in[1];
    const float* mn     = (const float*)d_in[2];
    const float* mx     = (const float*)d_in[3];
    float* out = (float*)d_out;

    const int B = in_sizes[2];      // 64
    const int H = 512, W = 512;

    float* partial = (float*)d_ws;  // 2048 floats

    const int nblocks = B * (H / 32) * 2;   // 2048 half-strip blocks
    gssim_strip<<<nblocks, NT, 0, stream>>>(pred, target, mn, mx, partial);

    const double inv_count = 1.0 / ((double)B * (double)H * (double)W);
    gssim_final<<<1, 256, 0, stream>>>(partial, nblocks, out, inv_count);
}

// Round 18
// 71.288 us; speedup vs baseline: 1.3213x; 1.3213x over previous
//
#include <hip/hip_runtime.h>
#include <hip/hip_fp16.h>
#include <math.h>

// GSSIM loss, persistent half-strip kernel (R18 = exact revert to R14, the
// session best: 71.4us). R15/R16/R17 structural probes all regressed (spill
// or work concentration); this restores the proven configuration.
//   - P3: 304 single-row units over 256 threads (threads 0-47 run 2 units).
//   - P2: uniform interior fast-path (no masks) for ~82% of tiles.
//   - staging: uniform fast-paths + packed f16 normalize.
// Grid 2048 half-strips (256x32, 8 tiles); LDS 32576 B -> 5 blocks/CU.
// Per tile: [B] stage -> P2 Sobel -> bar -> P3 H-sums -> bar ->
//           P4 V-sums+SSIM -> [A] spt write -> bar.
// Kernel 2: deterministic f64 reduce -> 1 - mean.

constexpr int NT = 256;
constexpr float EPS_F = 1e-6f;
constexpr float C1S = 2401.0f * 0.0001f;  // C1 * 49^2
constexpr float C2S = 2401.0f * 0.0009f;  // C2 * 49^2

union U4 { uint4 u; __half2 h[4]; };
union F4U { float4 v; float a[4]; };

__device__ __forceinline__ __half2 h2swap(__half2 x) {
    unsigned u = __builtin_bit_cast(unsigned, x);
    u = (u >> 16) | (u << 16);
    return __builtin_bit_cast(__half2, u);
}

__device__ __forceinline__ float ssim_px(__half2 apt, __half2 ag, __half2 agg, __half2 agx) {
    float2 vpt = __half22float2(apt);
    float2 vg  = __half22float2(ag);
    float2 vgg = __half22float2(agg);
    float  vgx = __low2float(agx);
    float lum_n = 2.0f * vpt.x * vpt.y + C1S;
    float lum_d = vpt.x * vpt.x + vpt.y * vpt.y + C1S;
    float cs_n  = 2.0f * (49.0f * vgx - vg.x * vg.y) + C2S;
    float cs_d  = 49.0f * (vgg.x + vgg.y) - vg.x * vg.x - vg.y * vg.y + C2S;
    return lum_n * cs_n * __builtin_amdgcn_rcpf(lum_d * cs_d);
}

__global__ __launch_bounds__(NT, 4)
void gssim_strip(const float* __restrict__ pred, const float* __restrict__ target,
                 const float* __restrict__ mn_arr, const float* __restrict__ mx_arr,
                 float* __restrict__ partial) {
    constexpr int H = 512, W = 512;
    __shared__ alignas(16) __half2 spt[40][44];      // 7040 B, stride 44 == 12 mod 32
    __shared__ alignas(16) __half2 sg[38][40];       // 6080 B
    __shared__ alignas(16) __half2 hsAll[38][32][4]; // 19456 B, rotated col=(c+k)&31
                                                     // total 32576 B -> 5 blocks/CU

    const int blk  = blockIdx.x;          // 0..2047
    const int b    = blk >> 5;            // image 0..63
    const int rem  = blk & 31;
    const int gy0  = (rem >> 1) * 32;     // strip top row
    const int tx0  = (rem & 1) * 8;       // first tile of this half-strip
    const int tid  = threadIdx.x;

    const float mn     = mn_arr[b];
    const float inv_dr = 1.0f / fmaxf(mx_arr[b] - mn, EPS_F);
    const __half2 mn2  = __float2half2_rn(mn);
    const __half2 inv2 = __float2half2_rn(inv_dr);
    const float* pimg = pred   + (size_t)b * H * W;
    const float* timg = target + (size_t)b * H * W;

    const bool rows_ok_all = (gy0 >= 4) && (gy0 + 35 < H);

    // staging: tid<200 owns input row pair (2*yr, 2*yr+1), col grp gS
    const int gS  = tid % 10;
    const int yr  = tid / 10;
    const int yS0 = 2 * yr, yS1 = yS0 + 1;
    const int gyS0 = gy0 - 4 + yS0;
    const int gyS1 = gyS0 + 1;
    const bool rok0 = (gyS0 >= 0 && gyS0 < H);
    const bool rok1 = (gyS1 >= 0 && gyS1 < H);
    const bool hasS = (tid < 200);

    F4U Pa0, Ta0, Pa1, Ta1;   // staged raw pixels (next tile)

    auto stage1m = [&](int gx0n, bool rowok, int gyI, F4U& P, F4U& T) {
        int gx = gx0n - 4 + 4 * gS;
        P.v = make_float4(0.f, 0.f, 0.f, 0.f);
        T.v = make_float4(0.f, 0.f, 0.f, 0.f);
        if (rowok) {
            if (gx >= 0 && gx + 4 <= W) {
                P.v = *reinterpret_cast<const float4*>(pimg + (size_t)gyI * W + gx);
                T.v = *reinterpret_cast<const float4*>(timg + (size_t)gyI * W + gx);
            } else {
#pragma unroll
                for (int c = 0; c < 4; ++c) {
                    int x = gx + c;
                    if (x >= 0 && x < W) {
                        P.a[c] = pimg[(size_t)gyI * W + x];
                        T.a[c] = timg[(size_t)gyI * W + x];
                    }
                }
            }
        }
    };
    auto stagePair = [&](int gx0n) {
        if (rows_ok_all && gx0n >= 4 && gx0n <= 448) {   // uniform fast path
            int gx = gx0n - 4 + 4 * gS;
            Pa0.v = *reinterpret_cast<const float4*>(pimg + (size_t)gyS0 * W + gx);
            Ta0.v = *reinterpret_cast<const float4*>(timg + (size_t)gyS0 * W + gx);
            Pa1.v = *reinterpret_cast<const float4*>(pimg + (size_t)gyS1 * W + gx);
            Ta1.v = *reinterpret_cast<const float4*>(timg + (size_t)gyS1 * W + gx);
        } else {
            stage1m(gx0n, rok0, gyS0, Pa0, Ta0);
            stage1m(gx0n, rok1, gyS1, Pa1, Ta1);
        }
    };

    auto normh2 = [&](float p, float t) {
        return __hmul2(__hsub2(__floats2half2_rn(p, t), mn2), inv2);
    };
    auto writePair = [&](int gx0n) {
        U4 w0, w1;
        if (rows_ok_all && gx0n >= 4 && gx0n <= 448) {   // uniform fast path
#pragma unroll
            for (int c = 0; c < 4; ++c) {
                w0.h[c] = normh2(Pa0.a[c], Ta0.a[c]);
                w1.h[c] = normh2(Pa1.a[c], Ta1.a[c]);
            }
        } else {
            int gx = gx0n - 4 + 4 * gS;
            const __half2 zero2l = __float2half2_rn(0.0f);
#pragma unroll
            for (int c = 0; c < 4; ++c) {
                int x = gx + c;
                bool okc = (x >= 0) && (x < W);
                w0.h[c] = (rok0 && okc) ? normh2(Pa0.a[c], Ta0.a[c]) : zero2l;
                w1.h[c] = (rok1 && okc) ? normh2(Pa1.a[c], Ta1.a[c]) : zero2l;
            }
        }
        *reinterpret_cast<uint4*>(&spt[yS0][4 * gS]) = w0.u;
        *reinterpret_cast<uint4*>(&spt[yS1][4 * gS]) = w1.u;
    };

    const __half2 two2  = __float2half2_rn(2.0f);
    const __half2 eps2  = __float2half2_rn(1e-6f);
    const __half2 zero2 = __float2half2_rn(0.0f);

    // prologue: stage + write first tile of this half-strip
    if (hasS) { stagePair(tx0 * 32); writePair(tx0 * 32); }
    __syncthreads();

    float accl = 0.0f;

    for (int tt = 0; tt < 8; ++tt) {
        const int gx0 = (tx0 + tt) * 32;
        const bool interior = rows_ok_all && (gx0 >= 32) && (gx0 <= 448);

        // ---- [B] issue next tile's loads (consumed after P4) ----
        if (tt < 7 && hasS) stagePair(gx0 + 32);

        // ---- P2: packed Sobel, row-pair tasks, shared spt loads ----
        if (tid < 190) {
            const int g  = tid % 10, kr = tid / 10;
            const int j0 = 4 * g, k0 = 2 * kr;
            __half2 a[4][6];
#pragma unroll
            for (int r = 0; r < 4; ++r) {
                U4 v; v.u = *reinterpret_cast<const uint4*>(&spt[k0 + r][j0]);
                a[r][0] = v.h[0]; a[r][1] = v.h[1]; a[r][2] = v.h[2]; a[r][3] = v.h[3];
                uint2 v2 = *reinterpret_cast<const uint2*>(&spt[k0 + r][j0 + 4]);
                a[r][4] = __builtin_bit_cast(__half2, v2.x);
                a[r][5] = __builtin_bit_cast(__half2, v2.y);
            }
            if (interior) {
#pragma unroll
                for (int rr = 0; rr < 2; ++rr) {
                    const int k = k0 + rr;
                    U4 w;
#pragma unroll
                    for (int c = 0; c < 4; ++c) {
                        __half2 gxh = __hsub2(a[rr][c + 2], a[rr][c]);
                        gxh = __hfma2(two2, __hsub2(a[rr + 1][c + 2], a[rr + 1][c]), gxh);
                        gxh = __hadd2(gxh, __hsub2(a[rr + 2][c + 2], a[rr + 2][c]));
                        __half2 gyh = __hsub2(a[rr + 2][c], a[rr][c]);
                        gyh = __hfma2(two2, __hsub2(a[rr + 2][c + 1], a[rr][c + 1]), gyh);
                        gyh = __hadd2(gyh, __hsub2(a[rr + 2][c + 2], a[rr][c + 2]));
                        w.h[c] = h2sqrt(__hfma2(gxh, gxh, __hfma2(gyh, gyh, eps2)));
                    }
                    *reinterpret_cast<uint4*>(&sg[k][j0]) = w.u;
                }
            } else {
                bool cm[4];
#pragma unroll
                for (int c = 0; c < 4; ++c) {
                    int gc = gx0 + j0 + c - 3;
                    cm[c] = (gc >= 0 && gc < W);
                }
#pragma unroll
                for (int rr = 0; rr < 2; ++rr) {
                    const int k = k0 + rr;
                    const int gr = gy0 + k - 3;
                    U4 w; w.h[0] = zero2; w.h[1] = zero2; w.h[2] = zero2; w.h[3] = zero2;
                    if (gr >= 0 && gr < H) {
#pragma unroll
                        for (int c = 0; c < 4; ++c) {
                            __half2 gxh = __hsub2(a[rr][c + 2], a[rr][c]);
                            gxh = __hfma2(two2, __hsub2(a[rr + 1][c + 2], a[rr + 1][c]), gxh);
                            gxh = __hadd2(gxh, __hsub2(a[rr + 2][c + 2], a[rr + 2][c]));
                            __half2 gyh = __hsub2(a[rr + 2][c], a[rr][c]);
                            gyh = __hfma2(two2, __hsub2(a[rr + 2][c + 1], a[rr][c + 1]), gyh);
                            gyh = __hadd2(gyh, __hsub2(a[rr + 2][c + 2], a[rr][c + 2]));
                            __half2 mag = h2sqrt(__hfma2(gxh, gxh, __hfma2(gyh, gyh, eps2)));
                            w.h[c] = cm[c] ? mag : zero2;
                        }
                    }
                    *reinterpret_cast<uint4*>(&sg[k][j0]) = w.u;
                }
            }
        }
        __syncthreads();

        // ---- P3: horizontal sliding 7-sums; 304 single-row units / 256 thr ----
        auto p3unit = [&](int t) {
            const int cg = t / 38;
            const int k  = t - cg * 38;   // consecutive across lanes: bank spread
            const int c0 = 4 * cg;
            __half2 ptv[12], sgv[12];
#pragma unroll
            for (int q = 0; q < 3; ++q) {
                U4 v; v.u = *reinterpret_cast<const uint4*>(&spt[k + 1][c0 + 4 * q]);
                ptv[4 * q] = v.h[0]; ptv[4 * q + 1] = v.h[1]; ptv[4 * q + 2] = v.h[2]; ptv[4 * q + 3] = v.h[3];
                U4 u; u.u = *reinterpret_cast<const uint4*>(&sg[k][c0 + 4 * q]);
                sgv[4 * q] = u.h[0]; sgv[4 * q + 1] = u.h[1]; sgv[4 * q + 2] = u.h[2]; sgv[4 * q + 3] = u.h[3];
            }
            __half2 gg[10], gx2[10];
#pragma unroll
            for (int q = 0; q < 10; ++q) {
                gg[q]  = __hmul2(sgv[q], sgv[q]);
                gx2[q] = __hmul2(sgv[q], h2swap(sgv[q]));
            }
            __half2 Hpt = ptv[1], Hg = sgv[0], Hgg = gg[0], Hgx = gx2[0];
#pragma unroll
            for (int q = 1; q < 7; ++q) {
                Hpt = __hadd2(Hpt, ptv[q + 1]);
                Hg  = __hadd2(Hg,  sgv[q]);
                Hgg = __hadd2(Hgg, gg[q]);
                Hgx = __hadd2(Hgx, gx2[q]);
            }
            U4 w0;
            w0.h[0] = Hpt; w0.h[1] = Hg; w0.h[2] = Hgg; w0.h[3] = Hgx;
            *reinterpret_cast<uint4*>(&hsAll[k][(c0 + k) & 31][0]) = w0.u;
#pragma unroll
            for (int m = 1; m < 4; ++m) {
                Hpt = __hadd2(__hsub2(Hpt, ptv[m]),      ptv[m + 7]);
                Hg  = __hadd2(__hsub2(Hg,  sgv[m - 1]),  sgv[m + 6]);
                Hgg = __hadd2(__hsub2(Hgg, gg[m - 1]),   gg[m + 6]);
                Hgx = __hadd2(__hsub2(Hgx, gx2[m - 1]),  gx2[m + 6]);
                U4 w;
                w.h[0] = Hpt; w.h[1] = Hg; w.h[2] = Hgg; w.h[3] = Hgx;
                *reinterpret_cast<uint4*>(&hsAll[k][(c0 + m + k) & 31][0]) = w.u;
            }
        };
        p3unit(tid);
        if (tid < 48) p3unit(tid + 256);
        __syncthreads();

        // ---- P4: per-column vertical sliding 7-sums + SSIM ----
        {
            const int ox = tid & 31;
            const int q  = tid >> 5;
            const int r0 = 4 * q;
            U4 win[10];
#pragma unroll
            for (int j = 0; j < 7; ++j) {
                int r = r0 + j;
                win[j].u = *reinterpret_cast<const uint4*>(&hsAll[r][(ox + r) & 31][0]);
            }
            __half2 Spt = win[0].h[0], Sg = win[0].h[1], Sgg = win[0].h[2], Sgx = win[0].h[3];
#pragma unroll
            for (int j = 1; j < 7; ++j) {
                Spt = __hadd2(Spt, win[j].h[0]);
                Sg  = __hadd2(Sg,  win[j].h[1]);
                Sgg = __hadd2(Sgg, win[j].h[2]);
                Sgx = __hadd2(Sgx, win[j].h[3]);
            }
            accl += ssim_px(Spt, Sg, Sgg, Sgx);
#pragma unroll
            for (int s = 1; s < 4; ++s) {
                int r = r0 + 6 + s;
                win[6 + s].u = *reinterpret_cast<const uint4*>(&hsAll[r][(ox + r) & 31][0]);
                Spt = __hadd2(__hsub2(Spt, win[s - 1].h[0]), win[6 + s].h[0]);
                Sg  = __hadd2(__hsub2(Sg,  win[s - 1].h[1]), win[6 + s].h[1]);
                Sgg = __hadd2(__hsub2(Sgg, win[s - 1].h[2]), win[6 + s].h[2]);
                Sgx = __hadd2(__hsub2(Sgx, win[s - 1].h[3]), win[6 + s].h[3]);
                accl += ssim_px(Spt, Sg, Sgg, Sgx);
            }
        }

        // ---- [A] write next tile's spt (staged loads have landed) ----
        if (tt < 7 && hasS) writePair(gx0 + 32);
        __syncthreads();
    }

    // ---- block reduction (deterministic); scratch overlaid on spt ----
    float* red = reinterpret_cast<float*>(&spt[0][0]);
#pragma unroll
    for (int off = 32; off > 0; off >>= 1) accl += __shfl_down(accl, off, 64);
    if ((tid & 63) == 0) red[tid >> 6] = accl;
    __syncthreads();
    if (tid == 0) partial[blk] = red[0] + red[1] + red[2] + red[3];
}

__global__ __launch_bounds__(256)
void gssim_final(const float* __restrict__ partial, int n,
                 float* __restrict__ out, double inv_count) {
    __shared__ double sred[256];
    double acc = 0.0;
    for (int i = threadIdx.x; i < n; i += 256) acc += (double)partial[i];
    sred[threadIdx.x] = acc;
    __syncthreads();
    for (int s = 128; s > 0; s >>= 1) {
        if ((int)threadIdx.x < s) sred[threadIdx.x] += sred[threadIdx.x + s];
        __syncthreads();
    }
    if (threadIdx.x == 0) out[0] = (float)(1.0 - sred[0] * inv_count);
}

extern "C" void kernel_launch(void* const* d_in, const int* in_sizes, int n_in,
                              void* d_out, int out_size, void* d_ws, size_t ws_size,
                              hipStream_t stream) {
    const float* pred   = (const float*)d_in[0];
    const float* target = (const float*)d_in[1];
    const float* mn     = (const float*)d_in[2];
    const float* mx     = (const float*)d_in[3];
    float* out = (float*)d_out;

    const int B = in_sizes[2];      // 64
    const int H = 512, W = 512;

    float* partial = (float*)d_ws;  // 2048 floats

    const int nblocks = B * (H / 32) * 2;   // 2048 half-strip blocks
    gssim_strip<<<nblocks, NT, 0, stream>>>(pred, target, mn, mx, partial);

    const double inv_count = 1.0 / ((double)B * (double)H * (double)W);
    gssim_final<<<1, 256, 0, stream>>>(partial, nblocks, out, inv_count);
}